// Round 1
// baseline (11258.794 us; speedup 1.0000x reference)
//
#include <hip/hip_runtime.h>
#include <math.h>

#define TB 512
#define NBATCH 32
#define TT 256
#define DD 256

// ---------------- workspace layout (float offsets) ----------------
#define WS_WF   0u            // fused Wf = composer_W @ writer_W  [512][1024]
#define WS_BF   524288u       // fused bias [1024]
#define WS_OSQ  525312u       // o_seq [256][32][256]
#define WS_PAR  2622464u      // partials [32][8][260]
#define WS_MRT  2689024u      // m_rt [32][256]
#define WS_RFAC 2697216u      // rescale factors [32][8]
#define WS_WHP  2697472u      // wh publish [32][256]
#define WS_BAR  2705664u      // barrier counters (ints, stride 32)
#define WS_FLOATS 2706048u

// ---------------- writer LDS layout (float offsets) ----------------
#define L_WR   0        // gate weights [32 cols][784]  (k regions of 192 + 4 pad)
#define WRS    784
#define L_MEM  25088    // mem slice [32 rows][260]
#define MS     260
#define L_ACT  33408    // act [4 batches][792]  ([o|m_rt|wh] w/ region pads)
#define AS     792
#define L_ZB   36576    // z buffer [4][32]
#define L_SS   36704    // scores [32]
#define L_SE   36736    // exp(scores - max) [32]
#define L_CS   36768    // c state [32]
#define L_BF   36800    // bias slice [32]
#define L_PM   36832    // reducer scratch [8]
#define L_PF   36840    // reducer scratch [8]
#define L_SC   36848    // scalars
#define DYN_LDS_BYTES 147456

// ---------------- reader LDS layout ----------------
#define R_W    0        // [32 cols][536] ([rW|rU] rows, k regions of 128 + 4 pad)
#define RWS    536
#define R_A    17152    // act [4][536]  ([x_t | h])
#define R_Z    19296    // [4][32]
#define R_B    19424    // bias [32]
#define R_C    19456    // c state [32]

__device__ __forceinline__ float hsig(float x) { return fminf(fmaxf(0.2f*x + 0.5f, 0.f), 1.f); }
__device__ __forceinline__ int akw(int k) { return k + 4*(k/192); }   // writer act/weight k->lds idx
__device__ __forceinline__ int akr(int k) { return k + 4*(k/128); }   // reader act/weight k->lds idx

// group/grid barrier: monotone counter, agent-scope. All WGs co-resident (cooperative launch).
__device__ __forceinline__ void barwait(int* cnt, int target) {
  __syncthreads();
  if (threadIdx.x == 0) {
    __threadfence();                 // release: drain our stores past L2 (cross-XCD safe)
    atomicAdd(cnt, 1);
    int sp = 0;
    while (__hip_atomic_load(cnt, __ATOMIC_RELAXED, __HIP_MEMORY_SCOPE_AGENT) < target) {
      if (++sp > (1 << 17)) break;   // safety: fail loud (wrong answer), never hang
    }
    __threadfence();                 // acquire: invalidate stale cached lines
  }
  __syncthreads();
}

__global__ void __launch_bounds__(TB) nse_kernel(
    const float* __restrict__ x,
    const float* __restrict__ rW, const float* __restrict__ rU, const float* __restrict__ rb,
    const float* __restrict__ wW, const float* __restrict__ wU, const float* __restrict__ wb,
    const float* __restrict__ cW, const float* __restrict__ cb,
    float* __restrict__ out, float* __restrict__ ws)
{
  extern __shared__ float sm[];
  const int tid = threadIdx.x;
  const int w = blockIdx.x;
  const int g = w >> 5;        // group (8 groups x 32 members); group owns batches 4g..4g+3
  const int m = w & 31;        // member: owns d-slice [8m,8m+8) cols for all 4 batches,
                               // and mem rows [32*(m&7), +32) of batch (m>>3)
  const int b0 = g * 4;

  float* Wf  = ws + WS_WF;
  float* bfv = ws + WS_BF;
  float* osq = ws + WS_OSQ;
  float* par = ws + WS_PAR;
  float* mrt = ws + WS_MRT;
  float* rfc = ws + WS_RFAC;
  float* whp = ws + WS_WHP;
  int*   bars = (int*)(ws + WS_BAR);
  int* gcnt = &bars[8*32];
  int* ccnt = &bars[g*32];

  // ---- barrier counter init (ws is poisoned 0xAA every launch) ----
  if (w == 0 && tid == 0) {
    for (int i = 0; i < 9; i++)
      __hip_atomic_store(&bars[i*32], 0, __ATOMIC_RELAXED, __HIP_MEMORY_SCOPE_AGENT);
    __hip_atomic_store(&bars[9*32], 1357911, __ATOMIC_RELEASE, __HIP_MEMORY_SCOPE_AGENT);
  }
  if (tid == 0) {
    int sp = 0;
    while (__hip_atomic_load(&bars[9*32], __ATOMIC_ACQUIRE, __HIP_MEMORY_SCOPE_AGENT) != 1357911) {
      if (++sp > (1 << 17)) break;
    }
  }
  __syncthreads();
  int gphase = 0, bphase = 0;

  // ================= fold: Wf = cW @ wW (tile 32k x 64n per WG), bf = cb@wW + wb =================
  {
    const int kt = w >> 4, nt = w & 15;
    const int r = tid >> 4, c4 = (tid & 15) * 4;
    float a0 = 0.f, a1 = 0.f, a2 = 0.f, a3 = 0.f;
    for (int jc = 0; jc < 512; jc += 32) {
      for (int u = tid; u < 1024; u += TB) {
        int rr = u >> 5, jj = u & 31;
        sm[rr*33 + jj] = cW[(32*kt + rr)*512 + jc + jj];
      }
      {
        int jj = tid >> 4, cc = (tid & 15) * 4;
        const float4 v = *(const float4*)&wW[(jc + jj)*1024 + 64*nt + cc];
        float* d = &sm[1056 + jj*68 + cc];
        d[0] = v.x; d[1] = v.y; d[2] = v.z; d[3] = v.w;
      }
      __syncthreads();
      #pragma unroll 8
      for (int j = 0; j < 32; j++) {
        const float a = sm[r*33 + j];
        const float* wv = &sm[1056 + j*68 + c4];
        a0 += a*wv[0]; a1 += a*wv[1]; a2 += a*wv[2]; a3 += a*wv[3];
      }
      __syncthreads();
    }
    float* d = &Wf[(32*kt + r)*1024 + 64*nt + c4];
    d[0] = a0; d[1] = a1; d[2] = a2; d[3] = a3;
  }
  if (w >= 16 && w < 32) {   // bias fold, 64 cols per WG
    __syncthreads();
    const int base = (w - 16) * 64;
    const int c = tid & 63, jq = tid >> 6;
    float p = 0.f;
    for (int j = 64*jq; j < 64*jq + 64; j++) p += cb[j] * wW[j*1024 + base + c];
    sm[jq*68 + c] = p;
    __syncthreads();
    if (tid < 64) {
      float s = wb[base + tid];
      for (int j = 0; j < 8; j++) s += sm[j*68 + tid];
      bfv[base + tid] = s;
    }
  }
  barwait(gcnt, 256 * (++gphase));

  // ================= READER: 256-step LSTM, group-local =================
  // stage member's [rW|rU] column slice into LDS (8-float contiguous gathers)
  for (int u = tid; u < 4096; u += TB) {
    const int k = u >> 3, rem = u & 7, gate = rem >> 1, half = rem & 1;
    const int colg = gate*256 + 8*m + 4*half;
    const float4 v = (k < 256) ? *(const float4*)&rW[k*1024 + colg]
                               : *(const float4*)&rU[(k - 256)*1024 + colg];
    const int cb2 = gate*8 + 4*half, ik = akr(k);
    sm[R_W + (cb2+0)*RWS + ik] = v.x;
    sm[R_W + (cb2+1)*RWS + ik] = v.y;
    sm[R_W + (cb2+2)*RWS + ik] = v.z;
    sm[R_W + (cb2+3)*RWS + ik] = v.w;
  }
  if (tid < 32) {
    sm[R_B + tid] = rb[(tid >> 3)*256 + 8*m + (tid & 7)];
    sm[R_C + tid] = 0.f;
  }
  __syncthreads();

  for (int t = 0; t < TT; t++) {
    // stage act = [x_t | h_{t-1}] for 4 batches
    for (int u = tid; u < 2048; u += TB) {
      const int part = u >> 10, lin = u & 1023, bl = lin >> 8, k = lin & 255;
      if (part == 0)
        sm[R_A + bl*RWS + akr(k)] = x[((b0+bl)*TT + t)*DD + k];
      else
        sm[R_A + bl*RWS + akr(256 + k)] = (t == 0) ? 0.f : osq[((t-1)*NBATCH + b0 + bl)*DD + k];
    }
    __syncthreads();
    {   // z = act @ [rW|rU] for my 32 cols x 4 batches; thread=(col,bl,q), k-quarter q
      const int col = tid >> 4, bl = (tid >> 2) & 3, q = tid & 3;
      const float* wr = &sm[R_W + col*RWS + 132*q];
      const float* ar = &sm[R_A + bl*RWS + 132*q];
      float acc = 0.f;
      #pragma unroll 8
      for (int kk = 0; kk < 128; kk += 4) {
        const float4 wv = *(const float4*)(wr + kk);
        const float4 av = *(const float4*)(ar + kk);
        acc += wv.x*av.x + wv.y*av.y + wv.z*av.z + wv.w*av.w;
      }
      acc += __shfl_xor(acc, 1, 64);
      acc += __shfl_xor(acc, 2, 64);
      if (q == 0) sm[R_Z + bl*32 + col] = acc + sm[R_B + col];
    }
    __syncthreads();
    if (tid < 32) {   // gates + state update for (bl, dl); publish h -> o_seq
      const int bl = tid >> 3, dl = tid & 7;
      const float zi = sm[R_Z + bl*32 + dl];
      const float zf = sm[R_Z + bl*32 + 8 + dl];
      const float zg = sm[R_Z + bl*32 + 16 + dl];
      const float zo = sm[R_Z + bl*32 + 24 + dl];
      const float cn = hsig(zf)*sm[R_C + tid] + hsig(zi)*tanhf(zg);
      sm[R_C + tid] = cn;
      osq[(t*NBATCH + b0 + bl)*DD + 8*m + dl] = hsig(zo)*tanhf(cn);
    }
    barwait(ccnt, 32 * (++bphase));
  }
  barwait(gcnt, 256 * (++gphase));

  // ================= WRITER: 256-step attention + LSTM =================
  const int blm = m >> 3;      // my batch (local) for mem slice
  const int isl = m & 7;       // my t-slice
  const int bmy = b0 + blm;

  // stage gate weight slice: rows = [Wf_top | Wf_bot | wU] (k=0..767)
  for (int u = tid; u < 6144; u += TB) {
    const int k = u >> 3, rem = u & 7, gate = rem >> 1, half = rem & 1;
    const int colg = gate*256 + 8*m + 4*half;
    const float4 v = (k < 512) ? *(const float4*)&Wf[k*1024 + colg]
                               : *(const float4*)&wU[(k - 512)*1024 + colg];
    const int cb2 = gate*8 + 4*half, ik = akw(k);
    sm[L_WR + (cb2+0)*WRS + ik] = v.x;
    sm[L_WR + (cb2+1)*WRS + ik] = v.y;
    sm[L_WR + (cb2+2)*WRS + ik] = v.z;
    sm[L_WR + (cb2+3)*WRS + ik] = v.w;
  }
  // mem slice init = x[bmy][32*isl .. +32][:]
  for (int u = tid; u < 8192; u += TB) {
    const int r = u >> 8, d2 = u & 255;
    sm[L_MEM + r*MS + d2] = x[(bmy*TT + 32*isl + r)*DD + d2];
  }
  // stage o_0, zero wh_prev
  for (int u = tid; u < 2048; u += TB) {
    const int part = u >> 10, lin = u & 1023, bl = lin >> 8, k = lin & 255;
    if (part == 0) sm[L_ACT + bl*AS + akw(k)] = osq[(b0 + bl)*DD + k];
    else           sm[L_ACT + bl*AS + akw(512 + k)] = 0.f;
  }
  if (tid < 32) {
    sm[L_BF + tid] = bfv[(tid >> 3)*256 + 8*m + (tid & 7)];
    sm[L_CS + tid] = 0.f;
  }
  __syncthreads();

  for (int t = 0; t < TT; t++) {
    // ---- W1: scores for my 32 mem rows vs o_t[bmy]; local online-softmax ----
    {
      const int r = tid >> 4, tk = tid & 15;
      const float* mrow = &sm[L_MEM + r*MS + 16*tk];
      const float* orow = &sm[L_ACT + blm*AS + 16*tk + ((tk >= 12) ? 4 : 0)];
      float acc = 0.f;
      #pragma unroll
      for (int i2 = 0; i2 < 16; i2 += 4) {
        const float4 mv = *(const float4*)(mrow + i2);
        const float4 ov = *(const float4*)(orow + i2);
        acc += mv.x*ov.x + mv.y*ov.y + mv.z*ov.z + mv.w*ov.w;
      }
      acc += __shfl_xor(acc, 1, 64); acc += __shfl_xor(acc, 2, 64);
      acc += __shfl_xor(acc, 4, 64); acc += __shfl_xor(acc, 8, 64);
      if (tk == 0) sm[L_SS + r] = acc;
    }
    __syncthreads();
    if (tid < 32) {
      const float s = sm[L_SS + tid];
      float mx = s;
      mx = fmaxf(mx, __shfl_xor(mx, 1, 64)); mx = fmaxf(mx, __shfl_xor(mx, 2, 64));
      mx = fmaxf(mx, __shfl_xor(mx, 4, 64)); mx = fmaxf(mx, __shfl_xor(mx, 8, 64));
      mx = fmaxf(mx, __shfl_xor(mx, 16, 64));
      const float e = __expf(s - mx);
      float su = e;
      su += __shfl_xor(su, 1, 64); su += __shfl_xor(su, 2, 64); su += __shfl_xor(su, 4, 64);
      su += __shfl_xor(su, 8, 64); su += __shfl_xor(su, 16, 64);
      sm[L_SE + tid] = e;
      if (tid == 0) { sm[L_SC + 0] = mx; sm[L_SC + 1] = su; }
    }
    __syncthreads();
    // ---- W2: P_i[d] = sum_r e_r * mem[r][d]; publish partials ----
    {
      const int dblk = tid >> 3, rh = tid & 7;
      float p0=0.f, p1=0.f, p2=0.f, p3=0.f;
      #pragma unroll
      for (int rr = 4*rh; rr < 4*rh + 4; rr++) {
        const float e = sm[L_SE + rr];
        const float* mp = &sm[L_MEM + rr*MS + 4*dblk];
        p0 += e*mp[0]; p1 += e*mp[1]; p2 += e*mp[2]; p3 += e*mp[3];
      }
      p0 += __shfl_xor(p0,1,64); p0 += __shfl_xor(p0,2,64); p0 += __shfl_xor(p0,4,64);
      p1 += __shfl_xor(p1,1,64); p1 += __shfl_xor(p1,2,64); p1 += __shfl_xor(p1,4,64);
      p2 += __shfl_xor(p2,1,64); p2 += __shfl_xor(p2,2,64); p2 += __shfl_xor(p2,4,64);
      p3 += __shfl_xor(p3,1,64); p3 += __shfl_xor(p3,2,64); p3 += __shfl_xor(p3,4,64);
      if (rh == 0) {
        float* d = &par[(bmy*8 + isl)*260 + 4*dblk];
        d[0]=p0; d[1]=p1; d[2]=p2; d[3]=p3;
      }
    }
    if (tid == 0) {
      par[(bmy*8 + isl)*260 + 256] = sm[L_SC + 0];
      par[(bmy*8 + isl)*260 + 257] = sm[L_SC + 1];
    }
    barwait(ccnt, 32 * (++bphase));   // B1
    // ---- W3: hierarchical softmax combine (members isl==0 reduce their batch) ----
    if (isl == 0) {
      if (tid < 8) {
        sm[L_PM + tid] = par[(bmy*8 + tid)*260 + 256];
        sm[L_PF + tid] = par[(bmy*8 + tid)*260 + 257];
      }
      __syncthreads();
      if (tid == 0) {
        float M = sm[L_PM + 0];
        for (int j = 1; j < 8; j++) M = fmaxf(M, sm[L_PM + j]);
        float tot = 0.f, f0[8];
        for (int j = 0; j < 8; j++) { f0[j] = __expf(sm[L_PM + j] - M); tot += f0[j]*sm[L_PF + j]; }
        const float inv = 1.f / tot;
        for (int j = 0; j < 8; j++) { const float rj = f0[j]*inv; sm[L_PM + j] = rj; rfc[bmy*8 + j] = rj; }
      }
      __syncthreads();
      if (tid < 256) {
        float a = 0.f;
        #pragma unroll
        for (int j = 0; j < 8; j++) a += sm[L_PM + j] * par[(bmy*8 + j)*260 + tid];
        mrt[bmy*256 + tid] = a;
      }
    }
    barwait(ccnt, 32 * (++bphase));   // B2
    // ---- W4: gates z = [o|m_rt|wh_prev] @ [Wf_top|Wf_bot|wU] + bf; LSTM update; publish wh ----
    for (int u = tid; u < 1024; u += TB) {
      const int bl = u >> 8, d2 = u & 255;
      sm[L_ACT + bl*AS + akw(256 + d2)] = mrt[(b0 + bl)*256 + d2];
    }
    if (tid == 0) sm[L_SC + 3] = rfc[bmy*8 + isl];
    __syncthreads();
    {
      const int col = tid >> 4, bl = (tid >> 2) & 3, q = tid & 3;
      const float* wr = &sm[L_WR + col*WRS + 196*q];
      const float* ar = &sm[L_ACT + bl*AS + 196*q];
      float acc = 0.f;
      #pragma unroll 8
      for (int kk = 0; kk < 192; kk += 4) {
        const float4 wv = *(const float4*)(wr + kk);
        const float4 av = *(const float4*)(ar + kk);
        acc += wv.x*av.x + wv.y*av.y + wv.z*av.z + wv.w*av.w;
      }
      acc += __shfl_xor(acc, 1, 64);
      acc += __shfl_xor(acc, 2, 64);
      if (q == 0) sm[L_ZB + bl*32 + col] = acc + sm[L_BF + col];
    }
    __syncthreads();
    if (tid < 32) {
      const int bl = tid >> 3, dl = tid & 7;
      const float zi = sm[L_ZB + bl*32 + dl];
      const float zf = sm[L_ZB + bl*32 + 8 + dl];
      const float zg = sm[L_ZB + bl*32 + 16 + dl];
      const float zo = sm[L_ZB + bl*32 + 24 + dl];
      const float cn = hsig(zf)*sm[L_CS + tid] + hsig(zi)*tanhf(zg);
      sm[L_CS + tid] = cn;
      const float hn = hsig(zo)*tanhf(cn);
      whp[(b0 + bl)*256 + 8*m + dl] = hn;
      if (t == TT-1) out[(b0 + bl)*256 + 8*m + dl] = hn;
    }
    barwait(ccnt, 32 * (++bphase));   // B3
    // ---- W5: stage wh (for next gates + update), update mem, prefetch o_{t+1} ----
    for (int u = tid; u < 1024; u += TB) {
      const int bl = u >> 8, d2 = u & 255;
      sm[L_ACT + bl*AS + akw(512 + d2)] = whp[(b0 + bl)*256 + d2];
    }
    __syncthreads();
    {
      const int r = tid >> 4, tk = tid & 15;
      const float zr = sm[L_SE + r] * sm[L_SC + 3];
      const float omz = 1.f - zr;
      float* mrow = &sm[L_MEM + r*MS + 16*tk];
      const float* hrow = &sm[L_ACT + blm*AS + akw(512 + 16*tk)];
      #pragma unroll
      for (int i2 = 0; i2 < 16; i2 += 4) {
        float4 mv = *(const float4*)(mrow + i2);
        const float4 hv = *(const float4*)(hrow + i2);
        mv.x = mv.x*omz + hv.x*zr;
        mv.y = mv.y*omz + hv.y*zr;
        mv.z = mv.z*omz + hv.z*zr;
        mv.w = mv.w*omz + hv.w*zr;
        *(float4*)(mrow + i2) = mv;
      }
    }
    if (t < TT-1) {
      for (int u = tid; u < 1024; u += TB) {
        const int bl = u >> 8, k = u & 255;
        sm[L_ACT + bl*AS + akw(k)] = osq[((t+1)*NBATCH + b0 + bl)*DD + k];
      }
    }
    __syncthreads();
  }
}

extern "C" void kernel_launch(void* const* d_in, const int* in_sizes, int n_in,
                              void* d_out, int out_size, void* d_ws, size_t ws_size,
                              hipStream_t stream) {
  (void)in_sizes; (void)n_in; (void)out_size;
  if (ws_size < (size_t)WS_FLOATS * 4u) {   // loud failure instead of corruption
    hipMemsetAsync(d_out, 0, (size_t)out_size * 4u, stream);
    return;
  }
  const float* x  = (const float*)d_in[0];
  const float* rW = (const float*)d_in[1];
  const float* rU = (const float*)d_in[2];
  const float* rb = (const float*)d_in[3];
  const float* wW = (const float*)d_in[4];
  const float* wU = (const float*)d_in[5];
  const float* wb = (const float*)d_in[6];
  const float* cW = (const float*)d_in[7];
  const float* cb = (const float*)d_in[8];
  float* out = (float*)d_out;
  float* ws  = (float*)d_ws;

  hipFuncSetAttribute((const void*)nse_kernel,
                      hipFuncAttributeMaxDynamicSharedMemorySize, DYN_LDS_BYTES);

  void* args[] = { (void*)&x, (void*)&rW, (void*)&rU, (void*)&rb,
                   (void*)&wW, (void*)&wU, (void*)&wb, (void*)&cW, (void*)&cb,
                   (void*)&out, (void*)&ws };
  hipError_t err = hipLaunchCooperativeKernel((const void*)nse_kernel,
                                              dim3(256), dim3(TB), args,
                                              DYN_LDS_BYTES, stream);
  if (err != hipSuccess) {
    // fallback: plain launch — grid == 1 WG/CU exactly fills the device
    nse_kernel<<<dim3(256), dim3(TB), DYN_LDS_BYTES, stream>>>(
        x, rW, rU, rb, wW, wU, wb, cW, cb, out, ws);
  }
}

// Round 2
// 3783.067 us; speedup vs baseline: 2.9761x; 2.9761x over previous
//
#include <hip/hip_runtime.h>
#include <math.h>

#define TB 512
#define NBATCH 32
#define TT 256
#define DD 256

// ---------------- workspace layout (float offsets) ----------------
#define WS_WF   0u            // fused Wf = composer_W @ writer_W  [512][1024]
#define WS_BF   524288u       // fused bias [1024]
#define WS_OSQ  525312u       // o_seq [256][32][256]
#define WS_PAR  2622464u      // partials [32 batches][8 slices][258]  (256 P + max + sum)
#define PS      258
#define WS_WHP  2688512u      // wh publish [32][256]
#define WS_BAR  2696704u      // barrier counters (ints, stride 32)
#define WS_FLOATS 2697088u

// ---------------- writer LDS layout (float offsets) ----------------
#define L_WR   0        // gate weights [32 cols][784]  (k regions of 192 + 4 pad)
#define WRS    784
#define L_MEM  25088    // mem slice [32 rows][260]
#define MS     260
#define L_ACT  33408    // act [4 batches][792]  ([o|m_rt|wh] w/ region pads)
#define AS     792
#define L_ZB   36576    // z buffer [4][32]
#define L_SS   36704    // scores [32]
#define L_SE   36736    // exp(scores - max) [32]
#define L_CS   36768    // c state [32]
#define L_BF   36800    // bias slice [32]
#define L_RJ   36832    // softmax combine weights [4][8]
#define L_MS   36864    // (max,sum) staging [4][8][2]
#define DYN_LDS_BYTES 147968

// ---------------- reader LDS layout ----------------
#define R_W    0        // [32 cols][536] ([rW|rU] rows, k regions of 128 + 4 pad)
#define RWS    536
#define R_A    17152    // act [4][536]  ([x_t | h])
#define R_Z    19296    // [4][32]
#define R_B    19424    // bias [32]
#define R_C    19456    // c state [32]

__device__ __forceinline__ float hsig(float x) { return fminf(fmaxf(0.2f*x + 0.5f, 0.f), 1.f); }
__device__ __forceinline__ int akw(int k) { return k + 4*(k/192); }   // writer act/weight k->lds idx
__device__ __forceinline__ int akr(int k) { return k + 4*(k/128); }   // reader act/weight k->lds idx

// Cross-WG data path: relaxed agent-scope atomics. These bypass the (non-
// cross-coherent) per-XCD L2 and complete at the shared L3 coherence point,
// so NO cache-maintenance fences are needed anywhere in the per-step loops.
__device__ __forceinline__ void gst(float* p, float v) {
  __hip_atomic_store(p, v, __ATOMIC_RELAXED, __HIP_MEMORY_SCOPE_AGENT);
}
__device__ __forceinline__ float gld(const float* p) {
  return __hip_atomic_load(p, __ATOMIC_RELAXED, __HIP_MEMORY_SCOPE_AGENT);
}

// Fence-free group barrier. Ordering argument: __syncthreads() lowers to
// s_waitcnt vmcnt(0) lgkmcnt(0) + s_barrier, so every thread's atomic data
// stores have completed at L3 before tid0 increments the counter; consumers
// observe the counter at L3 and then issue (in-order) their atomic data loads.
__device__ __forceinline__ void barrier_relaxed(int* cnt, int target) {
  __syncthreads();
  if (threadIdx.x == 0) {
    __hip_atomic_fetch_add(cnt, 1, __ATOMIC_RELAXED, __HIP_MEMORY_SCOPE_AGENT);
    int sp = 0;
    while (__hip_atomic_load(cnt, __ATOMIC_RELAXED, __HIP_MEMORY_SCOPE_AGENT) < target) {
      if (++sp > (1 << 18)) break;   // safety: fail loud (wrong answer), never hang
    }
  }
  __syncthreads();
}

// Fenced barrier — used ONCE (after the weight fold, whose output is written
// with normal stores and read later with normal loads).
__device__ __forceinline__ void barrier_fenced(int* cnt, int target) {
  __syncthreads();
  if (threadIdx.x == 0) {
    __threadfence();                 // release: write back dirty L2 (Wf tiles)
    __hip_atomic_fetch_add(cnt, 1, __ATOMIC_RELAXED, __HIP_MEMORY_SCOPE_AGENT);
    int sp = 0;
    while (__hip_atomic_load(cnt, __ATOMIC_RELAXED, __HIP_MEMORY_SCOPE_AGENT) < target) {
      if (++sp > (1 << 18)) break;
    }
    __threadfence();                 // acquire: invalidate stale L2 lines
  }
  __syncthreads();
}

__global__ void __launch_bounds__(TB) nse_kernel(
    const float* __restrict__ x,
    const float* __restrict__ rW, const float* __restrict__ rU, const float* __restrict__ rb,
    const float* __restrict__ wW, const float* __restrict__ wU, const float* __restrict__ wb,
    const float* __restrict__ cW, const float* __restrict__ cb,
    float* __restrict__ out, float* __restrict__ ws)
{
  extern __shared__ float sm[];
  const int tid = threadIdx.x;
  const int w = blockIdx.x;
  const int g = w >> 5;        // group (8 groups x 32 members); group owns batches 4g..4g+3
  const int m = w & 31;        // member: owns d-slice [8m,8m+8) cols for all 4 batches,
                               // and mem rows [32*(m&7), +32) of batch (m>>3)
  const int b0 = g * 4;

  float* Wf  = ws + WS_WF;
  float* bfv = ws + WS_BF;
  float* osq = ws + WS_OSQ;
  float* par = ws + WS_PAR;
  float* whp = ws + WS_WHP;
  int*   bars = (int*)(ws + WS_BAR);
  int* gcnt = &bars[8*32];
  int* ccnt = &bars[g*32];

  // ---- barrier counter init (ws is poisoned 0xAA every launch) ----
  if (w == 0 && tid == 0) {
    for (int i = 0; i < 9; i++)
      __hip_atomic_store(&bars[i*32], 0, __ATOMIC_RELAXED, __HIP_MEMORY_SCOPE_AGENT);
    __hip_atomic_store(&bars[9*32], 1357911, __ATOMIC_RELEASE, __HIP_MEMORY_SCOPE_AGENT);
  }
  if (tid == 0) {
    int sp = 0;
    while (__hip_atomic_load(&bars[9*32], __ATOMIC_ACQUIRE, __HIP_MEMORY_SCOPE_AGENT) != 1357911) {
      if (++sp > (1 << 18)) break;
    }
  }
  __syncthreads();
  int gphase = 0, bphase = 0;

  // ================= fold: Wf = cW @ wW (tile 32k x 64n per WG), bf = cb@wW + wb =================
  {
    const int kt = w >> 4, nt = w & 15;
    const int r = tid >> 4, c4 = (tid & 15) * 4;
    float a0 = 0.f, a1 = 0.f, a2 = 0.f, a3 = 0.f;
    for (int jc = 0; jc < 512; jc += 32) {
      for (int u = tid; u < 1024; u += TB) {
        int rr = u >> 5, jj = u & 31;
        sm[rr*33 + jj] = cW[(32*kt + rr)*512 + jc + jj];
      }
      {
        int jj = tid >> 4, cc = (tid & 15) * 4;
        const float4 v = *(const float4*)&wW[(jc + jj)*1024 + 64*nt + cc];
        float* d = &sm[1056 + jj*68 + cc];
        d[0] = v.x; d[1] = v.y; d[2] = v.z; d[3] = v.w;
      }
      __syncthreads();
      #pragma unroll 8
      for (int j = 0; j < 32; j++) {
        const float a = sm[r*33 + j];
        const float* wv = &sm[1056 + j*68 + c4];
        a0 += a*wv[0]; a1 += a*wv[1]; a2 += a*wv[2]; a3 += a*wv[3];
      }
      __syncthreads();
    }
    float* d = &Wf[(32*kt + r)*1024 + 64*nt + c4];
    d[0] = a0; d[1] = a1; d[2] = a2; d[3] = a3;
  }
  if (w >= 16 && w < 32) {   // bias fold, 64 cols per WG
    __syncthreads();
    const int base = (w - 16) * 64;
    const int c = tid & 63, jq = tid >> 6;
    float p = 0.f;
    for (int j = 64*jq; j < 64*jq + 64; j++) p += cb[j] * wW[j*1024 + base + c];
    sm[jq*68 + c] = p;
    __syncthreads();
    if (tid < 64) {
      float s = wb[base + tid];
      for (int j = 0; j < 8; j++) s += sm[j*68 + tid];
      bfv[base + tid] = s;
    }
  }
  barrier_fenced(gcnt, 256 * (++gphase));   // one-time fence: publishes Wf/bfv

  // ================= READER: 256-step LSTM, group-local =================
  for (int u = tid; u < 4096; u += TB) {
    const int k = u >> 3, rem = u & 7, gate = rem >> 1, half = rem & 1;
    const int colg = gate*256 + 8*m + 4*half;
    const float4 v = (k < 256) ? *(const float4*)&rW[k*1024 + colg]
                               : *(const float4*)&rU[(k - 256)*1024 + colg];
    const int cb2 = gate*8 + 4*half, ik = akr(k);
    sm[R_W + (cb2+0)*RWS + ik] = v.x;
    sm[R_W + (cb2+1)*RWS + ik] = v.y;
    sm[R_W + (cb2+2)*RWS + ik] = v.z;
    sm[R_W + (cb2+3)*RWS + ik] = v.w;
  }
  if (tid < 32) {
    sm[R_B + tid] = rb[(tid >> 3)*256 + 8*m + (tid & 7)];
    sm[R_C + tid] = 0.f;
  }
  // stage x_0
  for (int u = tid; u < 256; u += TB) {
    const int bl = u >> 6, k4 = (u & 63) * 4;
    const float4 v = *(const float4*)&x[(b0+bl)*TT*DD + k4];
    float* d = &sm[R_A + bl*RWS + akr(k4)];
    d[0] = v.x; d[1] = v.y; d[2] = v.z; d[3] = v.w;
  }
  __syncthreads();

  for (int t = 0; t < TT; t++) {
    // stage h_{t-1} (cross-WG, via L3 atomics)
    for (int u = tid; u < 1024; u += TB) {
      const int bl = u >> 8, k = u & 255;
      sm[R_A + bl*RWS + akr(256 + k)] = (t == 0) ? 0.f : gld(&osq[((t-1)*NBATCH + b0 + bl)*DD + k]);
    }
    __syncthreads();
    {   // z = act @ [rW|rU] for my 32 cols x 4 batches; thread=(col,bl,q), k-quarter q
      const int col = tid >> 4, bl = (tid >> 2) & 3, q = tid & 3;
      const float* wr = &sm[R_W + col*RWS + 132*q];
      const float* ar = &sm[R_A + bl*RWS + 132*q];
      float acc = 0.f;
      #pragma unroll 8
      for (int kk = 0; kk < 128; kk += 4) {
        const float4 wv = *(const float4*)(wr + kk);
        const float4 av = *(const float4*)(ar + kk);
        acc += wv.x*av.x + wv.y*av.y + wv.z*av.z + wv.w*av.w;
      }
      acc += __shfl_xor(acc, 1, 64);
      acc += __shfl_xor(acc, 2, 64);
      if (q == 0) sm[R_Z + bl*32 + col] = acc + sm[R_B + col];
    }
    __syncthreads();
    if (tid < 32) {   // gates + state update for (bl, dl); publish h -> o_seq
      const int bl = tid >> 3, dl = tid & 7;
      const float zi = sm[R_Z + bl*32 + dl];
      const float zf = sm[R_Z + bl*32 + 8 + dl];
      const float zg = sm[R_Z + bl*32 + 16 + dl];
      const float zo = sm[R_Z + bl*32 + 24 + dl];
      const float cn = hsig(zf)*sm[R_C + tid] + hsig(zi)*tanhf(zg);
      sm[R_C + tid] = cn;
      gst(&osq[(t*NBATCH + b0 + bl)*DD + 8*m + dl], hsig(zo)*tanhf(cn));
    }
    // overlap: stage x_{t+1} while others publish / barrier settles
    if (t < TT-1) {
      for (int u = tid; u < 256; u += TB) {
        const int bl = u >> 6, k4 = (u & 63) * 4;
        const float4 v = *(const float4*)&x[((b0+bl)*TT + t + 1)*DD + k4];
        float* d = &sm[R_A + bl*RWS + akr(k4)];
        d[0] = v.x; d[1] = v.y; d[2] = v.z; d[3] = v.w;
      }
    }
    barrier_relaxed(ccnt, 32 * (++bphase));
  }
  barrier_relaxed(gcnt, 256 * (++gphase));

  // ================= WRITER: 256-step attention + LSTM =================
  const int blm = m >> 3;      // my batch (local) for mem slice
  const int isl = m & 7;       // my t-slice
  const int bmy = b0 + blm;

  // stage gate weight slice: rows = [Wf_top | Wf_bot | wU] (k=0..767)
  for (int u = tid; u < 6144; u += TB) {
    const int k = u >> 3, rem = u & 7, gate = rem >> 1, half = rem & 1;
    const int colg = gate*256 + 8*m + 4*half;
    const float4 v = (k < 512) ? *(const float4*)&Wf[k*1024 + colg]
                               : *(const float4*)&wU[(k - 512)*1024 + colg];
    const int cb2 = gate*8 + 4*half, ik = akw(k);
    sm[L_WR + (cb2+0)*WRS + ik] = v.x;
    sm[L_WR + (cb2+1)*WRS + ik] = v.y;
    sm[L_WR + (cb2+2)*WRS + ik] = v.z;
    sm[L_WR + (cb2+3)*WRS + ik] = v.w;
  }
  // mem slice init = x[bmy][32*isl .. +32][:]
  for (int u = tid; u < 8192; u += TB) {
    const int r = u >> 8, d2 = u & 255;
    sm[L_MEM + r*MS + d2] = x[(bmy*TT + 32*isl + r)*DD + d2];
  }
  // stage o_0, zero wh_prev
  for (int u = tid; u < 2048; u += TB) {
    const int part = u >> 10, lin = u & 1023, bl = lin >> 8, k = lin & 255;
    if (part == 0) sm[L_ACT + bl*AS + akw(k)] = gld(&osq[(b0 + bl)*DD + k]);
    else           sm[L_ACT + bl*AS + akw(512 + k)] = 0.f;
  }
  if (tid < 32) {
    sm[L_BF + tid] = bfv[(tid >> 3)*256 + 8*m + (tid & 7)];
    sm[L_CS + tid] = 0.f;
  }
  __syncthreads();

  for (int t = 0; t < TT; t++) {
    // ---- W1: scores for my 32 mem rows vs o_t[bmy]; local softmax over slice ----
    {
      const int r = tid >> 4, tk = tid & 15;
      const float* mrow = &sm[L_MEM + r*MS + 16*tk];
      const float* orow = &sm[L_ACT + blm*AS + 16*tk + ((tk >= 12) ? 4 : 0)];
      float acc = 0.f;
      #pragma unroll
      for (int i2 = 0; i2 < 16; i2 += 4) {
        const float4 mv = *(const float4*)(mrow + i2);
        const float4 ov = *(const float4*)(orow + i2);
        acc += mv.x*ov.x + mv.y*ov.y + mv.z*ov.z + mv.w*ov.w;
      }
      acc += __shfl_xor(acc, 1, 64); acc += __shfl_xor(acc, 2, 64);
      acc += __shfl_xor(acc, 4, 64); acc += __shfl_xor(acc, 8, 64);
      if (tk == 0) sm[L_SS + r] = acc;
    }
    __syncthreads();
    if (tid < 32) {
      const float s = sm[L_SS + tid];
      float mx = s;
      mx = fmaxf(mx, __shfl_xor(mx, 1, 64)); mx = fmaxf(mx, __shfl_xor(mx, 2, 64));
      mx = fmaxf(mx, __shfl_xor(mx, 4, 64)); mx = fmaxf(mx, __shfl_xor(mx, 8, 64));
      mx = fmaxf(mx, __shfl_xor(mx, 16, 64));
      const float e = __expf(s - mx);
      float su = e;
      su += __shfl_xor(su, 1, 64); su += __shfl_xor(su, 2, 64); su += __shfl_xor(su, 4, 64);
      su += __shfl_xor(su, 8, 64); su += __shfl_xor(su, 16, 64);
      sm[L_SE + tid] = e;
      if (tid == 0) {
        gst(&par[(bmy*8 + isl)*PS + 256], mx);
        gst(&par[(bmy*8 + isl)*PS + 257], su);
      }
    }
    __syncthreads();
    // ---- W2: P_i[d] = sum_r e_r * mem[r][d]; publish partial slice ----
    {
      const int dblk = tid >> 3, rh = tid & 7;
      float p0=0.f, p1=0.f, p2=0.f, p3=0.f;
      #pragma unroll
      for (int rr = 4*rh; rr < 4*rh + 4; rr++) {
        const float e = sm[L_SE + rr];
        const float* mp = &sm[L_MEM + rr*MS + 4*dblk];
        p0 += e*mp[0]; p1 += e*mp[1]; p2 += e*mp[2]; p3 += e*mp[3];
      }
      p0 += __shfl_xor(p0,1,64); p0 += __shfl_xor(p0,2,64); p0 += __shfl_xor(p0,4,64);
      p1 += __shfl_xor(p1,1,64); p1 += __shfl_xor(p1,2,64); p1 += __shfl_xor(p1,4,64);
      p2 += __shfl_xor(p2,1,64); p2 += __shfl_xor(p2,2,64); p2 += __shfl_xor(p2,4,64);
      p3 += __shfl_xor(p3,1,64); p3 += __shfl_xor(p3,2,64); p3 += __shfl_xor(p3,4,64);
      if (rh == 0) {
        float* d = &par[(bmy*8 + isl)*PS + 4*dblk];
        gst(d+0, p0); gst(d+1, p1); gst(d+2, p2); gst(d+3, p3);
      }
    }
    barrier_relaxed(ccnt, 32 * (++bphase));   // B1: all partials at L3
    // ---- W3: redundant per-WG softmax combine (replaces reducer + 2nd barrier) ----
    if (tid < 64) {
      const int bl = tid >> 4, j = (tid >> 1) & 7, h2 = tid & 1;
      sm[L_MS + tid] = gld(&par[((b0+bl)*8 + j)*PS + 256 + h2]);   // [bl][j][h2]
    }
    __syncthreads();
    if (tid < 4) {
      const int bl = tid;
      float M = sm[L_MS + bl*16];
      for (int j = 1; j < 8; j++) M = fmaxf(M, sm[L_MS + bl*16 + 2*j]);
      float tot = 0.f, f0[8];
      for (int j = 0; j < 8; j++) {
        f0[j] = __expf(sm[L_MS + bl*16 + 2*j] - M);
        tot += f0[j] * sm[L_MS + bl*16 + 2*j + 1];
      }
      const float inv = 1.f / tot;
      for (int j = 0; j < 8; j++) sm[L_RJ + bl*8 + j] = f0[j]*inv;
    }
    __syncthreads();
    // m_rt[bl][d] = sum_j rj[bl][j] * P_j[bl][d]  -> straight into act region
    for (int u = tid; u < 1024; u += TB) {
      const int bl = u >> 8, d2 = u & 255;
      float a = 0.f;
      #pragma unroll
      for (int j = 0; j < 8; j++)
        a += sm[L_RJ + bl*8 + j] * gld(&par[((b0+bl)*8 + j)*PS + d2]);
      sm[L_ACT + bl*AS + akw(256 + d2)] = a;
    }
    __syncthreads();
    // ---- W4: gates z = [o|m_rt|wh_prev] @ [Wf_top|Wf_bot|wU] + bf; LSTM update ----
    {
      const int col = tid >> 4, bl = (tid >> 2) & 3, q = tid & 3;
      const float* wr = &sm[L_WR + col*WRS + 196*q];
      const float* ar = &sm[L_ACT + bl*AS + 196*q];
      float acc = 0.f;
      #pragma unroll 8
      for (int kk = 0; kk < 192; kk += 4) {
        const float4 wv = *(const float4*)(wr + kk);
        const float4 av = *(const float4*)(ar + kk);
        acc += wv.x*av.x + wv.y*av.y + wv.z*av.z + wv.w*av.w;
      }
      acc += __shfl_xor(acc, 1, 64);
      acc += __shfl_xor(acc, 2, 64);
      if (q == 0) sm[L_ZB + bl*32 + col] = acc + sm[L_BF + col];
    }
    __syncthreads();
    if (tid < 32) {
      const int bl = tid >> 3, dl = tid & 7;
      const float zi = sm[L_ZB + bl*32 + dl];
      const float zf = sm[L_ZB + bl*32 + 8 + dl];
      const float zg = sm[L_ZB + bl*32 + 16 + dl];
      const float zo = sm[L_ZB + bl*32 + 24 + dl];
      const float cn = hsig(zf)*sm[L_CS + tid] + hsig(zi)*tanhf(zg);
      sm[L_CS + tid] = cn;
      const float hn = hsig(zo)*tanhf(cn);
      if (t == TT-1) out[(b0 + bl)*256 + 8*m + dl] = hn;
      else           gst(&whp[(b0 + bl)*256 + 8*m + dl], hn);
    }
    if (t == TT-1) break;                      // no consumers of wh/mem after last step
    barrier_relaxed(ccnt, 32 * (++bphase));    // B3: wh at L3
    // ---- W5: stage wh, update mem, prefetch o_{t+1} ----
    for (int u = tid; u < 1024; u += TB) {
      const int bl = u >> 8, d2 = u & 255;
      sm[L_ACT + bl*AS + akw(512 + d2)] = gld(&whp[(b0 + bl)*256 + d2]);
    }
    __syncthreads();
    {
      const int r = tid >> 4, tk = tid & 15;
      const float zr = sm[L_SE + r] * sm[L_RJ + blm*8 + isl];
      const float omz = 1.f - zr;
      float* mrow = &sm[L_MEM + r*MS + 16*tk];
      const float* hrow = &sm[L_ACT + blm*AS + akw(512 + 16*tk)];
      #pragma unroll
      for (int i2 = 0; i2 < 16; i2 += 4) {
        float4 mv = *(const float4*)(mrow + i2);
        const float4 hv = *(const float4*)(hrow + i2);
        mv.x = mv.x*omz + hv.x*zr;
        mv.y = mv.y*omz + hv.y*zr;
        mv.z = mv.z*omz + hv.z*zr;
        mv.w = mv.w*omz + hv.w*zr;
        *(float4*)(mrow + i2) = mv;
      }
    }
    for (int u = tid; u < 1024; u += TB) {
      const int bl = u >> 8, k = u & 255;
      sm[L_ACT + bl*AS + akw(k)] = gld(&osq[((t+1)*NBATCH + b0 + bl)*DD + k]);
    }
    __syncthreads();
  }
}

extern "C" void kernel_launch(void* const* d_in, const int* in_sizes, int n_in,
                              void* d_out, int out_size, void* d_ws, size_t ws_size,
                              hipStream_t stream) {
  (void)in_sizes; (void)n_in;
  if (ws_size < (size_t)WS_FLOATS * 4u) {   // loud failure instead of corruption
    hipMemsetAsync(d_out, 0, (size_t)out_size * 4u, stream);
    return;
  }
  const float* x  = (const float*)d_in[0];
  const float* rW = (const float*)d_in[1];
  const float* rU = (const float*)d_in[2];
  const float* rb = (const float*)d_in[3];
  const float* wW = (const float*)d_in[4];
  const float* wU = (const float*)d_in[5];
  const float* wb = (const float*)d_in[6];
  const float* cW = (const float*)d_in[7];
  const float* cb = (const float*)d_in[8];
  float* out = (float*)d_out;
  float* ws  = (float*)d_ws;

  hipFuncSetAttribute((const void*)nse_kernel,
                      hipFuncAttributeMaxDynamicSharedMemorySize, DYN_LDS_BYTES);

  void* args[] = { (void*)&x, (void*)&rW, (void*)&rU, (void*)&rb,
                   (void*)&wW, (void*)&wU, (void*)&wb, (void*)&cW, (void*)&cb,
                   (void*)&out, (void*)&ws };
  hipError_t err = hipLaunchCooperativeKernel((const void*)nse_kernel,
                                              dim3(256), dim3(TB), args,
                                              DYN_LDS_BYTES, stream);
  if (err != hipSuccess) {
    // fallback: plain launch — grid == 1 WG/CU exactly fills the device
    nse_kernel<<<dim3(256), dim3(TB), DYN_LDS_BYTES, stream>>>(
        x, rW, rU, rb, wW, wU, wb, cW, cb, out, ws);
  }
}

// Round 3
// 3128.760 us; speedup vs baseline: 3.5985x; 1.2091x over previous
//
#include <hip/hip_runtime.h>
#include <math.h>

#define TB 512
#define NBATCH 32
#define TT 256
#define DD 256

typedef float f32x4 __attribute__((ext_vector_type(4)));

// ---------------- workspace layout (float offsets) ----------------
#define WS_WF   0u            // fused Wf = composer_W @ writer_W  [512][1024]
#define WS_BF   524288u       // fused bias [1024]
#define WS_HP   525312u       // h publish, double-buffered [2][32][256]
#define WS_PAR  541696u       // partials [32 batches][8 slices][260] (256 P + max + sum)
#define PS      260
#define WS_WHP  608256u       // wh publish [32][256]
#define WS_BAR  616448u       // barrier counters (ints, stride 32)
#define WS_FLOATS 616832u

// ---------------- LDS layout (float offsets) ----------------
#define O_WW    0        // writer weights [16 cols][784], akw rows
#define S_WW    784
#define O_RW    12544    // reader weights [16 cols][524], akr rows
#define S_RW    524
#define O_MEM   20928    // mem slice [32 rows][260]
#define S_MEM   260
#define O_WACT  29248    // writer act [8 bl][780]: [o|m_rt|wh], akw positions
#define S_WACT  780
#define O_RACT  35488    // reader act [8 bl][524]: [x|h], akr positions
#define S_RACT  524
#define O_WZ    39680    // [8][20]
#define O_RZ    39840    // [8][20]
#define O_SS    40000    // [32] raw scores
#define O_SE    40032    // [32] exp(s - local max)
#define O_WC    40064    // [32] writer c
#define O_RC    40096    // [32] reader c
#define O_WB    40128    // [16] writer bias slice
#define O_RB    40144    // [16] reader bias slice
#define O_RJ    40160    // [8 bl][8 j] softmax combine weights
#define O_MS    40224    // [8 bl][8 j][2] (max,sum) staging
#define LDS_FLOATS 40352
#define DYN_LDS_BYTES (LDS_FLOATS*4)   // 161,408 B

__device__ __forceinline__ float hsig(float x) { return fminf(fmaxf(0.2f*x + 0.5f, 0.f), 1.f); }
__device__ __forceinline__ int akw(int k) { return k + 4*(k/192); }   // writer k -> lds idx (pad 4/192)
__device__ __forceinline__ int akr(int k) { return k + 4*(k/128); }   // reader k -> lds idx (pad 4/128)

// scalar cross-WG ops: relaxed agent-scope atomics (L3 coherence point, no fences)
__device__ __forceinline__ void gst(float* p, float v) {
  __hip_atomic_store(p, v, __ATOMIC_RELAXED, __HIP_MEMORY_SCOPE_AGENT);
}
__device__ __forceinline__ float gld(const float* p) {
  return __hip_atomic_load(p, __ATOMIC_RELAXED, __HIP_MEMORY_SCOPE_AGENT);
}
// vector cross-WG ops: sc0+sc1 direct-to-L3, batched waitcnt
__device__ __forceinline__ void gst4(float* p, f32x4 v) {
  asm volatile("global_store_dwordx4 %0, %1, off sc0 sc1" :: "v"(p), "v"(v) : "memory");
}

// split barrier: arrive (drain own vmem, bump counter), slack work, wait
__device__ __forceinline__ void bar_arrive(int* cnt) {
  asm volatile("s_waitcnt vmcnt(0) lgkmcnt(0)" ::: "memory");
  __syncthreads();
  if (threadIdx.x == 0)
    __hip_atomic_fetch_add(cnt, 1, __ATOMIC_RELAXED, __HIP_MEMORY_SCOPE_AGENT);
}
__device__ __forceinline__ void bar_wait(int* cnt, int target) {
  if (threadIdx.x == 0) {
    int sp = 0;
    while (__hip_atomic_load(cnt, __ATOMIC_RELAXED, __HIP_MEMORY_SCOPE_AGENT) < target) {
      if (++sp > (1 << 20)) break;   // fail loud, never hang
    }
  }
  __syncthreads();
}
// fenced barrier — ONCE after the weight fold (normal stores/loads of Wf)
__device__ __forceinline__ void barrier_fenced(int* cnt, int target) {
  __syncthreads();
  if (threadIdx.x == 0) {
    __threadfence();
    __hip_atomic_fetch_add(cnt, 1, __ATOMIC_RELAXED, __HIP_MEMORY_SCOPE_AGENT);
    int sp = 0;
    while (__hip_atomic_load(cnt, __ATOMIC_RELAXED, __HIP_MEMORY_SCOPE_AGENT) < target) {
      if (++sp > (1 << 20)) break;
    }
    __threadfence();
  }
  __syncthreads();
}

__global__ void __launch_bounds__(TB) nse_kernel(
    const float* __restrict__ x,
    const float* __restrict__ rW, const float* __restrict__ rU, const float* __restrict__ rb,
    const float* __restrict__ wW, const float* __restrict__ wU, const float* __restrict__ wb,
    const float* __restrict__ cW, const float* __restrict__ cb,
    float* __restrict__ out, float* __restrict__ ws)
{
  extern __shared__ float sm[];
  const int tid = threadIdx.x;
  const int w = blockIdx.x;
  const int g = w >> 6;        // 4 groups x 64 members; group owns batches 8g..8g+7
  const int m = w & 63;        // member owns d-cols [4m,4m+4) for all 8 batches,
                               // and mem rows [32*(m&7), +32) of batch (m>>3)
  const int b0 = g * 8;
  const int blm = m >> 3;      // my mem batch (local)
  const int isl = m & 7;       // my mem t-slice
  const int bmy = b0 + blm;

  float* Wf   = ws + WS_WF;
  float* bfv  = ws + WS_BF;
  float* hpub = ws + WS_HP;
  float* par  = ws + WS_PAR;
  float* whp  = ws + WS_WHP;
  int*   bars = (int*)(ws + WS_BAR);
  int* gcnt = &bars[8*32];
  int* ccnt = &bars[g*32];

  // ---- barrier counter init (ws poisoned 0xAA every launch) ----
  if (w == 0 && tid == 0) {
    for (int i = 0; i < 9; i++)
      __hip_atomic_store(&bars[i*32], 0, __ATOMIC_RELAXED, __HIP_MEMORY_SCOPE_AGENT);
    __hip_atomic_store(&bars[9*32], 1357911, __ATOMIC_RELEASE, __HIP_MEMORY_SCOPE_AGENT);
  }
  if (tid == 0) {
    int sp = 0;
    while (__hip_atomic_load(&bars[9*32], __ATOMIC_ACQUIRE, __HIP_MEMORY_SCOPE_AGENT) != 1357911) {
      if (++sp > (1 << 20)) break;
    }
  }
  __syncthreads();

  // ================= fold: Wf = cW @ wW (32k x 64n per WG), bf = cb@wW + wb =================
  {
    const int kt = w >> 4, nt = w & 15;
    const int r = tid >> 4, c4 = (tid & 15) * 4;
    float a0 = 0.f, a1 = 0.f, a2 = 0.f, a3 = 0.f;
    for (int jc = 0; jc < 512; jc += 32) {
      for (int u = tid; u < 1024; u += TB) {
        int rr = u >> 5, jj = u & 31;
        sm[rr*33 + jj] = cW[(32*kt + rr)*512 + jc + jj];
      }
      {
        int jj = tid >> 4, cc = (tid & 15) * 4;
        const f32x4 v = *(const f32x4*)&wW[(jc + jj)*1024 + 64*nt + cc];
        float* d = &sm[1056 + jj*68 + cc];
        d[0] = v.x; d[1] = v.y; d[2] = v.z; d[3] = v.w;
      }
      __syncthreads();
      #pragma unroll 8
      for (int j = 0; j < 32; j++) {
        const float a = sm[r*33 + j];
        const float* wv = &sm[1056 + j*68 + c4];
        a0 += a*wv[0]; a1 += a*wv[1]; a2 += a*wv[2]; a3 += a*wv[3];
      }
      __syncthreads();
    }
    float* d = &Wf[(32*kt + r)*1024 + 64*nt + c4];
    d[0] = a0; d[1] = a1; d[2] = a2; d[3] = a3;
  }
  if (w >= 16 && w < 32) {   // bias fold
    __syncthreads();
    const int base = (w - 16) * 64;
    const int c = tid & 63, jq = tid >> 6;
    float p = 0.f;
    for (int j = 64*jq; j < 64*jq + 64; j++) p += cb[j] * wW[j*1024 + base + c];
    sm[jq*68 + c] = p;
    __syncthreads();
    if (tid < 64) {
      float s = wb[base + tid];
      for (int j = 0; j < 8; j++) s += sm[j*68 + tid];
      bfv[base + tid] = s;
    }
  }
  barrier_fenced(gcnt, 256);

  // ================= init: stage weights, mem, biases; zero state =================
  for (int u = tid; u < 3072; u += TB) {        // writer [Wf|wU] col slice
    const int k = u >> 2, gate = u & 3;
    const float* sp = (k < 512) ? &Wf[(size_t)k*1024 + gate*256 + 4*m]
                                : &wU[(size_t)(k-512)*1024 + gate*256 + 4*m];
    const f32x4 v = *(const f32x4*)sp;
    const int ik = akw(k);
    sm[O_WW + (gate*4+0)*S_WW + ik] = v.x;
    sm[O_WW + (gate*4+1)*S_WW + ik] = v.y;
    sm[O_WW + (gate*4+2)*S_WW + ik] = v.z;
    sm[O_WW + (gate*4+3)*S_WW + ik] = v.w;
  }
  for (int u = tid; u < 2048; u += TB) {        // reader [rW|rU] col slice
    const int k = u >> 2, gate = u & 3;
    const float* sp = (k < 256) ? &rW[(size_t)k*1024 + gate*256 + 4*m]
                                : &rU[(size_t)(k-256)*1024 + gate*256 + 4*m];
    const f32x4 v = *(const f32x4*)sp;
    const int ik = akr(k);
    sm[O_RW + (gate*4+0)*S_RW + ik] = v.x;
    sm[O_RW + (gate*4+1)*S_RW + ik] = v.y;
    sm[O_RW + (gate*4+2)*S_RW + ik] = v.z;
    sm[O_RW + (gate*4+3)*S_RW + ik] = v.w;
  }
  for (int u = tid; u < 2048; u += TB) {        // mem slice init = x[bmy][32*isl..][:]
    const int r = u >> 6, d4 = (u & 63) * 4;
    *(f32x4*)&sm[O_MEM + r*S_MEM + d4] =
        *(const f32x4*)&x[((size_t)bmy*TT + 32*isl + r)*DD + d4];
  }
  for (int u = tid; u < LDS_FLOATS - O_WACT; u += TB) sm[O_WACT + u] = 0.f;
  if (tid < 16) {
    const int gate = tid >> 2, dl = tid & 3;
    sm[O_WB + tid] = bfv[gate*256 + 4*m + dl];
    sm[O_RB + tid] = rb[gate*256 + 4*m + dl];
  }
  __syncthreads();

  // ================= merged loop: reader step s (s<=255), writer step t=s-1 (s>=1) =================
  int bphase = 0;
  for (int s = 0; s <= TT; s++) {
    // ---- stage: h_{s-1}, wh_{s-2} (L3 vector loads), x_s (plain) ----
    {
      const int bl = tid >> 6, d4 = (tid & 63) * 4;
      f32x4 vh, vw;
      const float* ph = &hpub[(size_t)((s+1)&1)*8192 + (b0+bl)*256 + d4];
      const float* pw = &whp[(b0+bl)*256 + d4];
      asm volatile(
        "global_load_dwordx4 %0, %2, off sc0 sc1\n\t"
        "global_load_dwordx4 %1, %3, off sc0 sc1\n\t"
        "s_waitcnt vmcnt(0)"
        : "=&v"(vh), "=&v"(vw) : "v"(ph), "v"(pw) : "memory");
      if (s >= 1) {
        *(f32x4*)&sm[O_RACT + bl*S_RACT + akr(256 + d4)] = vh;   // reader h-in / W1 o
        *(f32x4*)&sm[O_WACT + bl*S_WACT + akw(d4)]       = vh;   // writer GEMV o
      }
      if (s >= 2)
        *(f32x4*)&sm[O_WACT + bl*S_WACT + akw(512 + d4)] = vw;   // writer GEMV wh-in + mem upd
      if (s <= TT-1)
        *(f32x4*)&sm[O_RACT + bl*S_RACT + akr(d4)] =
            *(const f32x4*)&x[((size_t)(b0+bl)*TT + s)*DD + d4];
    }
    __syncthreads();

    // ---- W1 (s>=1): fused lazy mem-update (wh_{s-2}, z from step s-1) + scores vs o ----
    if (s >= 1) {
      const int r = tid >> 4, tk = tid & 15;
      float* mrow = &sm[O_MEM + r*S_MEM + 16*tk];
      const float* orow = &sm[O_RACT + blm*S_RACT + akr(256 + 16*tk)];
      float acc = 0.f;
      if (s >= 2) {
        const float zr = sm[O_SE + r] * sm[O_RJ + blm*8 + isl];
        const float omz = 1.f - zr;
        const float* hrow = &sm[O_WACT + blm*S_WACT + akw(512 + 16*tk)];
        #pragma unroll
        for (int i2 = 0; i2 < 16; i2 += 4) {
          f32x4 mv = *(f32x4*)(mrow + i2);
          const f32x4 hv = *(const f32x4*)(hrow + i2);
          const f32x4 ov = *(const f32x4*)(orow + i2);
          mv.x = mv.x*omz + hv.x*zr;  mv.y = mv.y*omz + hv.y*zr;
          mv.z = mv.z*omz + hv.z*zr;  mv.w = mv.w*omz + hv.w*zr;
          *(f32x4*)(mrow + i2) = mv;
          acc += mv.x*ov.x + mv.y*ov.y + mv.z*ov.z + mv.w*ov.w;
        }
      } else {
        #pragma unroll
        for (int i2 = 0; i2 < 16; i2 += 4) {
          const f32x4 mv = *(const f32x4*)(mrow + i2);
          const f32x4 ov = *(const f32x4*)(orow + i2);
          acc += mv.x*ov.x + mv.y*ov.y + mv.z*ov.z + mv.w*ov.w;
        }
      }
      acc += __shfl_xor(acc, 1, 64); acc += __shfl_xor(acc, 2, 64);
      acc += __shfl_xor(acc, 4, 64); acc += __shfl_xor(acc, 8, 64);
      if (tk == 0) sm[O_SS + r] = acc;
    }
    __syncthreads();
    if (s >= 1 && tid < 32) {   // local softmax over my 32 rows
      const float sc = sm[O_SS + tid];
      float mx = sc;
      mx = fmaxf(mx, __shfl_xor(mx, 1, 64)); mx = fmaxf(mx, __shfl_xor(mx, 2, 64));
      mx = fmaxf(mx, __shfl_xor(mx, 4, 64)); mx = fmaxf(mx, __shfl_xor(mx, 8, 64));
      mx = fmaxf(mx, __shfl_xor(mx, 16, 64));
      const float e = __expf(sc - mx);
      float su = e;
      su += __shfl_xor(su, 1, 64); su += __shfl_xor(su, 2, 64); su += __shfl_xor(su, 4, 64);
      su += __shfl_xor(su, 8, 64); su += __shfl_xor(su, 16, 64);
      sm[O_SE + tid] = e;
      if (tid == 0) {
        gst(&par[((size_t)bmy*8 + isl)*PS + 256], mx);
        gst(&par[((size_t)bmy*8 + isl)*PS + 257], su);
      }
    }
    __syncthreads();
    // ---- W2 (s>=1): P_isl[d] = sum_r e_r mem[r][d]; vector publish ----
    if (s >= 1) {
      const int dblk = tid >> 3, rh = tid & 7;
      f32x4 p; p.x = 0.f; p.y = 0.f; p.z = 0.f; p.w = 0.f;
      #pragma unroll
      for (int i = 0; i < 4; i++) {
        const int rr = 4*rh + i;
        const float e = sm[O_SE + rr];
        const f32x4 mv = *(const f32x4*)&sm[O_MEM + rr*S_MEM + 4*dblk];
        p.x += e*mv.x; p.y += e*mv.y; p.z += e*mv.z; p.w += e*mv.w;
      }
      p.x += __shfl_xor(p.x,1,64); p.x += __shfl_xor(p.x,2,64); p.x += __shfl_xor(p.x,4,64);
      p.y += __shfl_xor(p.y,1,64); p.y += __shfl_xor(p.y,2,64); p.y += __shfl_xor(p.y,4,64);
      p.z += __shfl_xor(p.z,1,64); p.z += __shfl_xor(p.z,2,64); p.z += __shfl_xor(p.z,4,64);
      p.w += __shfl_xor(p.w,1,64); p.w += __shfl_xor(p.w,2,64); p.w += __shfl_xor(p.w,4,64);
      if (rh == 0) gst4(&par[((size_t)bmy*8 + isl)*PS + 4*dblk], p);
    }
    ++bphase; bar_arrive(ccnt);            // ---- barrier A arrive (partials) ----

    // ---- slack: reader GEMV + gates + h publish (s<=255) ----
    if (s <= TT-1) {
      const int q  = tid & 3;
      const int cl = ((tid >> 4) & 3) + 4 * (tid >> 7);
      const int bl = ((tid >> 2) & 3) + 4 * ((tid >> 6) & 1);
      const float* wr = &sm[O_RW + cl*S_RW + 132*q];
      const float* ar = &sm[O_RACT + bl*S_RACT + 132*q];
      float acc = 0.f;
      #pragma unroll
      for (int kk = 0; kk < 128; kk += 4) {
        const f32x4 wv = *(const f32x4*)(wr + kk);
        const f32x4 av = *(const f32x4*)(ar + kk);
        acc += wv.x*av.x + wv.y*av.y + wv.z*av.z + wv.w*av.w;
      }
      acc += __shfl_xor(acc, 1, 64);
      acc += __shfl_xor(acc, 2, 64);
      if (q == 0) sm[O_RZ + bl*20 + cl] = acc + sm[O_RB + cl];
    }
    __syncthreads();
    if (s <= TT-1 && tid < 32) {
      const int bl = tid >> 2, dl = tid & 3;
      const float zi = sm[O_RZ + bl*20 + dl];
      const float zf = sm[O_RZ + bl*20 + 4 + dl];
      const float zg = sm[O_RZ + bl*20 + 8 + dl];
      const float zo = sm[O_RZ + bl*20 + 12 + dl];
      const float cn = hsig(zf)*sm[O_RC + tid] + hsig(zi)*tanhf(zg);
      sm[O_RC + tid] = cn;
      gst(&hpub[(size_t)(s&1)*8192 + (b0+bl)*256 + 4*m + dl], hsig(zo)*tanhf(cn));
    }
    bar_wait(ccnt, 64*bphase);             // ---- barrier A wait ----

    if (s >= 1) {
      // ---- combine: redundant softmax merge + m_rt (batched L3 vector loads) ----
      if (tid < 128) {
        const int bl = tid >> 4, j = (tid >> 1) & 7, h2 = tid & 1;
        sm[O_MS + bl*16 + j*2 + h2] = gld(&par[((size_t)(b0+bl)*8 + j)*PS + 256 + h2]);
      }
      __syncthreads();
      if (tid < 8) {
        const int bl = tid;
        float M = sm[O_MS + bl*16];
        for (int j = 1; j < 8; j++) M = fmaxf(M, sm[O_MS + bl*16 + 2*j]);
        float tot = 0.f, f0[8];
        for (int j = 0; j < 8; j++) {
          f0[j] = __expf(sm[O_MS + bl*16 + 2*j] - M);
          tot += f0[j] * sm[O_MS + bl*16 + 2*j + 1];
        }
        const float inv = 1.f / tot;
        for (int j = 0; j < 8; j++) sm[O_RJ + bl*8 + j] = f0[j]*inv;
      }
      __syncthreads();
      {
        const int bl = tid >> 6, d4 = (tid & 63) * 4;
        const float* p0 = &par[((size_t)(b0+bl)*8 + 0)*PS + d4];
        const float* p4 = p0 + 4*PS;
        f32x4 v0,v1,v2,v3,v4,v5,v6,v7;
        asm volatile(
          "global_load_dwordx4 %0, %8, off sc0 sc1\n\t"
          "global_load_dwordx4 %1, %8, off offset:1040 sc0 sc1\n\t"
          "global_load_dwordx4 %2, %8, off offset:2080 sc0 sc1\n\t"
          "global_load_dwordx4 %3, %8, off offset:3120 sc0 sc1\n\t"
          "global_load_dwordx4 %4, %9, off sc0 sc1\n\t"
          "global_load_dwordx4 %5, %9, off offset:1040 sc0 sc1\n\t"
          "global_load_dwordx4 %6, %9, off offset:2080 sc0 sc1\n\t"
          "global_load_dwordx4 %7, %9, off offset:3120 sc0 sc1\n\t"
          "s_waitcnt vmcnt(0)"
          : "=&v"(v0),"=&v"(v1),"=&v"(v2),"=&v"(v3),
            "=&v"(v4),"=&v"(v5),"=&v"(v6),"=&v"(v7)
          : "v"(p0), "v"(p4) : "memory");
        const float* rj = &sm[O_RJ + bl*8];
        f32x4 a;
        a.x = rj[0]*v0.x + rj[1]*v1.x + rj[2]*v2.x + rj[3]*v3.x
            + rj[4]*v4.x + rj[5]*v5.x + rj[6]*v6.x + rj[7]*v7.x;
        a.y = rj[0]*v0.y + rj[1]*v1.y + rj[2]*v2.y + rj[3]*v3.y
            + rj[4]*v4.y + rj[5]*v5.y + rj[6]*v6.y + rj[7]*v7.y;
        a.z = rj[0]*v0.z + rj[1]*v1.z + rj[2]*v2.z + rj[3]*v3.z
            + rj[4]*v4.z + rj[5]*v5.z + rj[6]*v6.z + rj[7]*v7.z;
        a.w = rj[0]*v0.w + rj[1]*v1.w + rj[2]*v2.w + rj[3]*v3.w
            + rj[4]*v4.w + rj[5]*v5.w + rj[6]*v6.w + rj[7]*v7.w;
        *(f32x4*)&sm[O_WACT + bl*S_WACT + akw(256 + d4)] = a;
      }
      __syncthreads();
      // ---- writer gates GEMV: z = [o|m_rt|wh] @ [Wf|wU]-slice + bf ----
      {
        const int q  = tid & 3;
        const int cl = ((tid >> 4) & 3) + 4 * (tid >> 7);
        const int bl = ((tid >> 2) & 3) + 4 * ((tid >> 6) & 1);
        const float* wr = &sm[O_WW + cl*S_WW + 196*q];
        const float* ar = &sm[O_WACT + bl*S_WACT + 196*q];
        float acc = 0.f;
        #pragma unroll
        for (int kk = 0; kk < 192; kk += 4) {
          const f32x4 wv = *(const f32x4*)(wr + kk);
          const f32x4 av = *(const f32x4*)(ar + kk);
          acc += wv.x*av.x + wv.y*av.y + wv.z*av.z + wv.w*av.w;
        }
        acc += __shfl_xor(acc, 1, 64);
        acc += __shfl_xor(acc, 2, 64);
        if (q == 0) sm[O_WZ + bl*20 + cl] = acc + sm[O_WB + cl];
      }
      __syncthreads();
      if (tid < 32) {   // writer LSTM update + publish wh (or out at last step)
        const int bl = tid >> 2, dl = tid & 3;
        const float zi = sm[O_WZ + bl*20 + dl];
        const float zf = sm[O_WZ + bl*20 + 4 + dl];
        const float zg = sm[O_WZ + bl*20 + 8 + dl];
        const float zo = sm[O_WZ + bl*20 + 12 + dl];
        const float cn = hsig(zf)*sm[O_WC + tid] + hsig(zi)*tanhf(zg);
        sm[O_WC + tid] = cn;
        const float hn = hsig(zo)*tanhf(cn);
        if (s == TT) out[(b0+bl)*256 + 4*m + dl] = hn;
        else         gst(&whp[(b0+bl)*256 + 4*m + dl], hn);
      }
    }
    ++bphase; bar_arrive(ccnt);            // ---- barrier B (wh + h_s) ----
    bar_wait(ccnt, 64*bphase);
  }
}

extern "C" void kernel_launch(void* const* d_in, const int* in_sizes, int n_in,
                              void* d_out, int out_size, void* d_ws, size_t ws_size,
                              hipStream_t stream) {
  (void)in_sizes; (void)n_in;
  if (ws_size < (size_t)WS_FLOATS * 4u) {   // loud failure instead of corruption
    hipMemsetAsync(d_out, 0, (size_t)out_size * 4u, stream);
    return;
  }
  const float* x  = (const float*)d_in[0];
  const float* rW = (const float*)d_in[1];
  const float* rU = (const float*)d_in[2];
  const float* rb = (const float*)d_in[3];
  const float* wW = (const float*)d_in[4];
  const float* wU = (const float*)d_in[5];
  const float* wb = (const float*)d_in[6];
  const float* cW = (const float*)d_in[7];
  const float* cb = (const float*)d_in[8];
  float* out = (float*)d_out;
  float* ws  = (float*)d_ws;

  hipFuncSetAttribute((const void*)nse_kernel,
                      hipFuncAttributeMaxDynamicSharedMemorySize, DYN_LDS_BYTES);

  void* args[] = { (void*)&x, (void*)&rW, (void*)&rU, (void*)&rb,
                   (void*)&wW, (void*)&wU, (void*)&wb, (void*)&cW, (void*)&cb,
                   (void*)&out, (void*)&ws };
  hipError_t err = hipLaunchCooperativeKernel((const void*)nse_kernel,
                                              dim3(256), dim3(TB), args,
                                              DYN_LDS_BYTES, stream);
  if (err != hipSuccess) {
    nse_kernel<<<dim3(256), dim3(TB), DYN_LDS_BYTES, stream>>>(
        x, rW, rU, rb, wW, wU, wb, cW, cb, out, ws);
  }
}